// Round 2
// baseline (198.596 us; speedup 1.0000x reference)
//
#include <hip/hip_runtime.h>

#define B_ 2
#define L_ 256
#define D_ 512
#define H_ 8
#define DV_ 64
#define NEGINF 1e12f

// ws layout (floats):
#define WS_VALUE 0
#define WS_WR    262144
#define WS_SSRC  266240
#define WS_STGT  270336

// ---------------- Kernel A: WR[k][h] = sum_d W_relation[k][h*64+d] * w_rel[h][d]
__global__ __launch_bounds__(256) void k_wr(const float* __restrict__ Wrel,
                                            const float* __restrict__ wrel,
                                            float* __restrict__ WR) {
    int flat = blockIdx.x * 256 + threadIdx.x;   // 4096 = 512*8
    int k = flat >> 3, h = flat & 7;
    const float* a = Wrel + k * 512 + h * 64;
    const float* b = wrel + h * 64;
    float s = 0.f;
#pragma unroll
    for (int d = 0; d < 64; d += 4) {
        float4 x = *(const float4*)(a + d);
        float4 y = *(const float4*)(b + d);
        s += x.x * y.x + x.y * y.y + x.z * y.z + x.w * y.w;
    }
    WR[k * 8 + h] = s;
}

// ---------------- Kernel B: value[b][h][l][dv] = sum_k inp[b][l][k] * W_value[k][h*64+dv]
__global__ __launch_bounds__(256) void k_value(const float* __restrict__ inp,
                                               const float* __restrict__ Wv,
                                               float* __restrict__ value) {
    int blk = blockIdx.x;          // 256 blocks = 128 row-tiles x 2 col-halves
    int ct  = blk & 1;
    int rt  = blk >> 1;
    int n   = ct * 256 + threadIdx.x;   // output col 0..511
    int r0  = rt * 4;
    const float* i0 = inp + (size_t)(r0 + 0) * 512;
    const float* i1 = inp + (size_t)(r0 + 1) * 512;
    const float* i2 = inp + (size_t)(r0 + 2) * 512;
    const float* i3 = inp + (size_t)(r0 + 3) * 512;
    float a0 = 0.f, a1 = 0.f, a2 = 0.f, a3 = 0.f;
#pragma unroll 8
    for (int k = 0; k < 512; ++k) {
        float w = Wv[(size_t)k * 512 + n];
        a0 = fmaf(i0[k], w, a0);
        a1 = fmaf(i1[k], w, a1);
        a2 = fmaf(i2[k], w, a2);
        a3 = fmaf(i3[k], w, a3);
    }
    int h = n >> 6, dv = n & 63;
    float acc[4] = {a0, a1, a2, a3};
#pragma unroll
    for (int r = 0; r < 4; ++r) {
        int row = r0 + r;
        int b = row >> 8, l = row & 255;
        value[(((size_t)(b * 8 + h)) * 256 + l) * 64 + dv] = acc[r];
    }
}

// ---------------- Kernel C: s_src/s_tgt[b][h][j] = dot(value[b][h][j][:], w_{src,tgt}[h][:])
__global__ __launch_bounds__(256) void k_src_tgt(const float* __restrict__ value,
                                                 const float* __restrict__ wsrc,
                                                 const float* __restrict__ wtgt,
                                                 float* __restrict__ s_src,
                                                 float* __restrict__ s_tgt) {
    int flat = blockIdx.x * 256 + threadIdx.x;   // 4096 = (b*8+h)*256 + j
    int h = (flat >> 8) & 7;
    const float* v  = value + (size_t)flat * 64;
    const float* ws = wsrc + h * 64;
    const float* wt = wtgt + h * 64;
    float ss = 0.f, st = 0.f;
#pragma unroll
    for (int d = 0; d < 64; d += 4) {
        float4 x = *(const float4*)(v + d);
        float4 s4 = *(const float4*)(ws + d);
        float4 t4 = *(const float4*)(wt + d);
        ss += x.x * s4.x + x.y * s4.y + x.z * s4.z + x.w * s4.w;
        st += x.x * t4.x + x.y * t4.y + x.z * t4.z + x.w * t4.w;
    }
    s_src[flat] = ss;
    s_tgt[flat] = st;
}

// ---------------- Kernel D: fused s_rel + scores + softmax + attn fixups + out
__global__ __launch_bounds__(256) void k_main(const float* __restrict__ rel,    // [b][i][j][k]
                                              const int*   __restrict__ mask,   // [b][i][j]
                                              const float* __restrict__ adj,    // [b][h][i][j]
                                              const float* __restrict__ inp,    // [b][i][D]
                                              const float* __restrict__ value,  // [b][h][j][dv]
                                              const float* __restrict__ WR,     // [k][h]
                                              const float* __restrict__ s_src,  // [b][h][j]
                                              const float* __restrict__ s_tgt,  // [b][h][i]
                                              float* __restrict__ out) {        // [b][i][D]
    __shared__ float srel[256 * 8];    // [j][h]
    __shared__ float attn[8][256];
    int bi  = blockIdx.x;           // b*256 + i
    int b   = bi >> 8;
    int i   = bi & 255;
    int tid = threadIdx.x;

    // ---- Phase 1: srel[j][h] = rel[b,i,j,:] . WR[:,h]
    // Wave-cooperative rows: lane = (c<<3)|h, c = k-chunk 0..7, h = head 0..7.
    // Lane's k set: {c*4 + it*32 + e}, it=0..15, e=0..3 (float4 at byte 16c+128it
    // -> each VMEM instr covers one contiguous 128B segment, 8-way broadcast).
    {
        int lane = tid & 63;
        int w    = tid >> 6;        // wave 0..3, owns rows [w*64, w*64+64)
        int h    = lane & 7;
        int c    = lane >> 3;

        float WRc[64];              // WR[k][h] for this lane's 64 k's (fixed)
#pragma unroll
        for (int it = 0; it < 16; ++it)
#pragma unroll
            for (int e = 0; e < 4; ++e)
                WRc[it * 4 + e] = WR[(c * 4 + it * 32 + e) * 8 + h];

        const float* rowbase = rel + ((size_t)bi * 256 + w * 64) * 512 + c * 4;
        for (int jj = 0; jj < 64; jj += 2) {
            const float* r0 = rowbase + (size_t)jj * 512;
            const float* r1 = r0 + 512;
            float a0 = 0.f, a1 = 0.f, a2 = 0.f, a3 = 0.f;
            float b0 = 0.f, b1 = 0.f, b2 = 0.f, b3 = 0.f;
#pragma unroll
            for (int it = 0; it < 16; ++it) {
                float4 x = *(const float4*)(r0 + it * 32);
                float4 y = *(const float4*)(r1 + it * 32);
                a0 = fmaf(x.x, WRc[it * 4 + 0], a0);
                a1 = fmaf(x.y, WRc[it * 4 + 1], a1);
                a2 = fmaf(x.z, WRc[it * 4 + 2], a2);
                a3 = fmaf(x.w, WRc[it * 4 + 3], a3);
                b0 = fmaf(y.x, WRc[it * 4 + 0], b0);
                b1 = fmaf(y.y, WRc[it * 4 + 1], b1);
                b2 = fmaf(y.z, WRc[it * 4 + 2], b2);
                b3 = fmaf(y.w, WRc[it * 4 + 3], b3);
            }
            float s0 = (a0 + a1) + (a2 + a3);
            float s1 = (b0 + b1) + (b2 + b3);
            // reduce over chunk axis c (lane bits 3..5)
#pragma unroll
            for (int off = 8; off <= 32; off <<= 1) {
                s0 += __shfl_xor(s0, off);
                s1 += __shfl_xor(s1, off);
            }
            if (lane < 8) {   // c==0, h==lane
                int j = w * 64 + jj;
                srel[j * 8 + lane]       = s0;
                srel[(j + 1) * 8 + lane] = s1;
            }
        }
    }
    __syncthreads();

    // ---- Phase 2: per (h) row softmax over j; 32 lanes per h, 8 j per lane
    {
        int h  = tid >> 5;
        int ln = tid & 31;
        float stgt = s_tgt[(size_t)(b * 8 + h) * 256 + i];
        const float* ssrc   = s_src + (size_t)(b * 8 + h) * 256;
        const float* adjrow = adj + ((size_t)(b * 8 + h) * 256 + i) * 256;
        const int*   mrow   = mask + (size_t)bi * 256;

        float sc[8], av[8];
        int mb = 0;
        float rowmax = -3.0e38f;
#pragma unroll
        for (int t = 0; t < 8; ++t) {
            int j = ln + 32 * t;
            float a = adjrow[j];
            av[t] = a;
            int m = mrow[j];
            float s = ssrc[j] + stgt + srel[j * 8 + h];
            s = (s >= 0.f) ? s : 0.2f * s;     // leaky relu on the sum
            if (m != 0) { s = -NEGINF; mb |= (1 << t); }
            if (a == 0.f) s = -NEGINF;
            sc[t] = s;
            rowmax = fmaxf(rowmax, s);
        }
#pragma unroll
        for (int off = 16; off >= 1; off >>= 1)
            rowmax = fmaxf(rowmax, __shfl_xor(rowmax, off));

        float rowsum = 0.f;
#pragma unroll
        for (int t = 0; t < 8; ++t) {
            sc[t] = expf(sc[t] - rowmax);
            rowsum += sc[t];
        }
#pragma unroll
        for (int off = 16; off >= 1; off >>= 1)
            rowsum += __shfl_xor(rowsum, off);

        float sumabs = 0.f;
#pragma unroll
        for (int t = 0; t < 8; ++t) {
            float p = sc[t] / rowsum;
            float invv = (av[t] == 0.f) ? 1e-12f : (1.0f / av[t]);
            p *= invv;
            sc[t] = p;
            sumabs += fabsf(p);
        }
#pragma unroll
        for (int off = 16; off >= 1; off >>= 1)
            sumabs += __shfl_xor(sumabs, off);

        float rdn = 1.0f / fmaxf(sumabs, 1e-12f);
#pragma unroll
        for (int t = 0; t < 8; ++t) {
            float p = sc[t] * rdn;
            if (mb & (1 << t)) p = 0.f;
            if (av[t] == 0.f) p = 0.f;
            attn[h][ln + 32 * t] = p;
        }
    }
    __syncthreads();

    // ---- Phase 3: out[b][i][h*64+d] = inp + sum_j attn[h][j] * value[b][h][j][d]
    {
        int h  = tid >> 5;
        int d0 = (tid & 31) * 2;
        const float* vbase = value + ((size_t)(b * 8 + h) * 256) * 64 + d0;
        float ax = 0.f, ay = 0.f;
#pragma unroll 4
        for (int j = 0; j < 256; ++j) {
            float a = attn[h][j];
            float2 v2 = *(const float2*)(vbase + (size_t)j * 64);
            ax = fmaf(a, v2.x, ax);
            ay = fmaf(a, v2.y, ay);
        }
        size_t o = (size_t)bi * 512 + h * 64 + d0;
        out[o]     = inp[o] + ax;
        out[o + 1] = inp[o + 1] + ay;
    }
}

extern "C" void kernel_launch(void* const* d_in, const int* in_sizes, int n_in,
                              void* d_out, int out_size, void* d_ws, size_t ws_size,
                              hipStream_t stream) {
    const float* inp      = (const float*)d_in[0];
    const float* rel      = (const float*)d_in[1];
    const int*   mask     = (const int*)  d_in[2];
    const float* adj      = (const float*)d_in[3];
    const float* W_value  = (const float*)d_in[4];
    const float* W_rel    = (const float*)d_in[5];
    const float* w_src    = (const float*)d_in[6];
    const float* w_tgt    = (const float*)d_in[7];
    const float* w_rel    = (const float*)d_in[8];
    float* out = (float*)d_out;

    float* ws    = (float*)d_ws;
    float* value = ws + WS_VALUE;
    float* WR    = ws + WS_WR;
    float* s_src = ws + WS_SSRC;
    float* s_tgt = ws + WS_STGT;

    k_wr<<<16, 256, 0, stream>>>(W_rel, w_rel, WR);
    k_value<<<256, 256, 0, stream>>>(inp, W_value, value);
    k_src_tgt<<<16, 256, 0, stream>>>(value, w_src, w_tgt, s_src, s_tgt);
    k_main<<<B_ * L_, 256, 0, stream>>>(rel, mask, adj, inp, value, WR,
                                        s_src, s_tgt, out);
}

// Round 3
// 114.770 us; speedup vs baseline: 1.7304x; 1.7304x over previous
//
#include <hip/hip_runtime.h>

#define B_ 2
#define L_ 256
#define D_ 512
#define H_ 8
#define DV_ 64
#define NEGINF 1e12f

// ws layout (floats):
#define WS_VALUE 0
#define WS_WR    262144
#define WS_SSRC  266240
#define WS_STGT  270336

// ---------------- Kernel A: WR[k][h] = sum_d W_relation[k][h*64+d] * w_rel[h][d]
__global__ __launch_bounds__(256) void k_wr(const float* __restrict__ Wrel,
                                            const float* __restrict__ wrel,
                                            float* __restrict__ WR) {
    int flat = blockIdx.x * 256 + threadIdx.x;   // 4096 = 512*8
    int k = flat >> 3, h = flat & 7;
    const float* a = Wrel + k * 512 + h * 64;
    const float* b = wrel + h * 64;
    float s = 0.f;
#pragma unroll
    for (int d = 0; d < 64; d += 4) {
        float4 x = *(const float4*)(a + d);
        float4 y = *(const float4*)(b + d);
        s += x.x * y.x + x.y * y.y + x.z * y.z + x.w * y.w;
    }
    WR[k * 8 + h] = s;
}

// ---------------- Kernel B: value[b][h][l][dv] = sum_k inp[b][l][k] * W_value[k][h*64+dv]
__global__ __launch_bounds__(256) void k_value(const float* __restrict__ inp,
                                               const float* __restrict__ Wv,
                                               float* __restrict__ value) {
    int blk = blockIdx.x;          // 256 blocks = 128 row-tiles x 2 col-halves
    int ct  = blk & 1;
    int rt  = blk >> 1;
    int n   = ct * 256 + threadIdx.x;   // output col 0..511
    int r0  = rt * 4;
    const float* i0 = inp + (size_t)(r0 + 0) * 512;
    const float* i1 = inp + (size_t)(r0 + 1) * 512;
    const float* i2 = inp + (size_t)(r0 + 2) * 512;
    const float* i3 = inp + (size_t)(r0 + 3) * 512;
    float a0 = 0.f, a1 = 0.f, a2 = 0.f, a3 = 0.f;
#pragma unroll 8
    for (int k = 0; k < 512; ++k) {
        float w = Wv[(size_t)k * 512 + n];
        a0 = fmaf(i0[k], w, a0);
        a1 = fmaf(i1[k], w, a1);
        a2 = fmaf(i2[k], w, a2);
        a3 = fmaf(i3[k], w, a3);
    }
    int h = n >> 6, dv = n & 63;
    float acc[4] = {a0, a1, a2, a3};
#pragma unroll
    for (int r = 0; r < 4; ++r) {
        int row = r0 + r;
        int b = row >> 8, l = row & 255;
        value[(((size_t)(b * 8 + h)) * 256 + l) * 64 + dv] = acc[r];
    }
}

// ---------------- Kernel C: s_src/s_tgt[b][h][j] = dot(value[b][h][j][:], w_{src,tgt}[h][:])
__global__ __launch_bounds__(256) void k_src_tgt(const float* __restrict__ value,
                                                 const float* __restrict__ wsrc,
                                                 const float* __restrict__ wtgt,
                                                 float* __restrict__ s_src,
                                                 float* __restrict__ s_tgt) {
    int flat = blockIdx.x * 256 + threadIdx.x;   // 4096 = (b*8+h)*256 + j
    int h = (flat >> 8) & 7;
    const float* v  = value + (size_t)flat * 64;
    const float* ws = wsrc + h * 64;
    const float* wt = wtgt + h * 64;
    float ss = 0.f, st = 0.f;
#pragma unroll
    for (int d = 0; d < 64; d += 4) {
        float4 x = *(const float4*)(v + d);
        float4 s4 = *(const float4*)(ws + d);
        float4 t4 = *(const float4*)(wt + d);
        ss += x.x * s4.x + x.y * s4.y + x.z * s4.z + x.w * s4.w;
        st += x.x * t4.x + x.y * t4.y + x.z * t4.z + x.w * t4.w;
    }
    s_src[flat] = ss;
    s_tgt[flat] = st;
}

// ---------------- Kernel D: fused s_rel (LDS-tiled GEMM) + softmax + out
// Block = one (b,i). 256 threads. Thread t owns j-row t.
__global__ __launch_bounds__(256) void k_main(const float* __restrict__ rel,    // [bi][j][k]
                                              const int*   __restrict__ mask,   // [bi][j]
                                              const float* __restrict__ adj,    // [b][h][i][j]
                                              const float* __restrict__ inp,    // [bi][D]
                                              const float* __restrict__ value,  // [b][h][j][dv]
                                              const float* __restrict__ WR,     // [k][h]
                                              const float* __restrict__ s_src,  // [b][h][j]
                                              const float* __restrict__ s_tgt,  // [b][h][i]
                                              float* __restrict__ out) {        // [bi][D]
    __shared__ float tile[256 * 64];   // 64 KB; reused for srel/attn after phase 1
    int bi  = blockIdx.x;
    int b   = bi >> 8;
    int i   = bi & 255;
    int tid = threadIdx.x;

    // ---- Phase 1: acc[h] = rel[bi, t, :] . WR[:, h], k-tiled through LDS
    float acc[8];
#pragma unroll
    for (int h = 0; h < 8; ++h) acc[h] = 0.f;

    const float* relbase = rel + (size_t)bi * 256 * 512;

    for (int kt = 0; kt < 8; ++kt) {
        int k0 = kt * 64;
        // stage: 256 rows x 64 floats (64 KB), coalesced 256B row-slices
#pragma unroll
        for (int ii = 0; ii < 16; ++ii) {
            int f = ii * 256 + tid;        // float4 index 0..4095
            int r = f >> 4;                // row 0..255
            int c = f & 15;                // logical chunk 0..15
            float4 v = *(const float4*)(relbase + (size_t)r * 512 + k0 + c * 4);
            int w = r * 64 + ((c ^ (r & 15)) << 2);   // XOR-swizzled word
            *(float4*)&tile[w] = v;
        }
        __syncthreads();

        const float* wrt = WR + k0 * 8;    // wave-uniform -> s_load
#pragma unroll
        for (int c = 0; c < 16; ++c) {
            float4 x = *(const float4*)&tile[tid * 64 + ((c ^ (tid & 15)) << 2)];
#pragma unroll
            for (int h = 0; h < 8; ++h) {
                acc[h] = fmaf(x.x, wrt[(c * 4 + 0) * 8 + h],
                         fmaf(x.y, wrt[(c * 4 + 1) * 8 + h],
                         fmaf(x.z, wrt[(c * 4 + 2) * 8 + h],
                         fmaf(x.w, wrt[(c * 4 + 3) * 8 + h], acc[h]))));
            }
        }
        __syncthreads();
    }

    // publish srel: tile[h*256 + j]  (j = tid)
    float* srel_s = tile;          // 8*256 floats
    float* attn_s = tile + 2048;   // 8*256 floats
#pragma unroll
    for (int h = 0; h < 8; ++h) srel_s[h * 256 + tid] = acc[h];
    __syncthreads();

    // ---- Phase 2: per-h row softmax over j; 32 lanes per h, 8 j per lane
    {
        int h  = tid >> 5;
        int ln = tid & 31;
        float stgt = s_tgt[(size_t)(b * 8 + h) * 256 + i];
        const float* ssrc   = s_src + (size_t)(b * 8 + h) * 256;
        const float* adjrow = adj + ((size_t)(b * 8 + h) * 256 + i) * 256;
        const int*   mrow   = mask + (size_t)bi * 256;

        float sc[8], av[8];
        int mb = 0;
        float rowmax = -3.0e38f;
#pragma unroll
        for (int t = 0; t < 8; ++t) {
            int j = ln + 32 * t;
            float a = adjrow[j];
            av[t] = a;
            int m = mrow[j];
            float s = ssrc[j] + stgt + srel_s[h * 256 + j];
            s = (s >= 0.f) ? s : 0.2f * s;     // leaky relu
            if (m != 0) { s = -NEGINF; mb |= (1 << t); }
            if (a == 0.f) s = -NEGINF;
            sc[t] = s;
            rowmax = fmaxf(rowmax, s);
        }
#pragma unroll
        for (int off = 16; off >= 1; off >>= 1)
            rowmax = fmaxf(rowmax, __shfl_xor(rowmax, off));

        float rowsum = 0.f;
#pragma unroll
        for (int t = 0; t < 8; ++t) {
            sc[t] = expf(sc[t] - rowmax);
            rowsum += sc[t];
        }
#pragma unroll
        for (int off = 16; off >= 1; off >>= 1)
            rowsum += __shfl_xor(rowsum, off);

        float sumabs = 0.f;
#pragma unroll
        for (int t = 0; t < 8; ++t) {
            float p = sc[t] / rowsum;
            float invv = (av[t] == 0.f) ? 1e-12f : (1.0f / av[t]);
            p *= invv;
            sc[t] = p;
            sumabs += fabsf(p);
        }
#pragma unroll
        for (int off = 16; off >= 1; off >>= 1)
            sumabs += __shfl_xor(sumabs, off);

        float rdn = 1.0f / fmaxf(sumabs, 1e-12f);
#pragma unroll
        for (int t = 0; t < 8; ++t) {
            float p = sc[t] * rdn;
            if (mb & (1 << t)) p = 0.f;
            if (av[t] == 0.f) p = 0.f;
            attn_s[h * 256 + ln + 32 * t] = p;
        }
    }
    __syncthreads();

    // ---- Phase 3: out[bi][h*64+d] = inp + sum_j attn[h][j] * value[b][h][j][d]
    {
        int h  = tid >> 5;
        int d0 = (tid & 31) * 2;
        const float* vbase = value + ((size_t)(b * 8 + h) * 256) * 64 + d0;
        const float* arow  = attn_s + h * 256;
        float ax = 0.f, ay = 0.f;
#pragma unroll 4
        for (int j = 0; j < 256; ++j) {
            float a = arow[j];
            float2 v2 = *(const float2*)(vbase + (size_t)j * 64);
            ax = fmaf(a, v2.x, ax);
            ay = fmaf(a, v2.y, ay);
        }
        size_t o = (size_t)bi * 512 + h * 64 + d0;
        out[o]     = inp[o] + ax;
        out[o + 1] = inp[o + 1] + ay;
    }
}

extern "C" void kernel_launch(void* const* d_in, const int* in_sizes, int n_in,
                              void* d_out, int out_size, void* d_ws, size_t ws_size,
                              hipStream_t stream) {
    const float* inp      = (const float*)d_in[0];
    const float* rel      = (const float*)d_in[1];
    const int*   mask     = (const int*)  d_in[2];
    const float* adj      = (const float*)d_in[3];
    const float* W_value  = (const float*)d_in[4];
    const float* W_rel    = (const float*)d_in[5];
    const float* w_src    = (const float*)d_in[6];
    const float* w_tgt    = (const float*)d_in[7];
    const float* w_rel    = (const float*)d_in[8];
    float* out = (float*)d_out;

    float* ws    = (float*)d_ws;
    float* value = ws + WS_VALUE;
    float* WR    = ws + WS_WR;
    float* s_src = ws + WS_SSRC;
    float* s_tgt = ws + WS_STGT;

    k_wr<<<16, 256, 0, stream>>>(W_rel, w_rel, WR);
    k_value<<<256, 256, 0, stream>>>(inp, W_value, value);
    k_src_tgt<<<16, 256, 0, stream>>>(value, w_src, w_tgt, s_src, s_tgt);
    k_main<<<B_ * L_, 256, 0, stream>>>(rel, mask, adj, inp, value, WR,
                                        s_src, s_tgt, out);
}